// Round 13
// baseline (138.754 us; speedup 1.0000x reference)
//
#include <hip/hip_runtime.h>
#include <hip/hip_bf16.h>

// Mex forward: B=64,C=64,H=W=64, BLK=(64,3,3), STR=(64,2,2), PAD=(0,1,1),
// NI=256, EPS=1, mean mode. OH=OW=32, K=576, out (64,256,32,32) fp32.
//
// y[n][i] = log( sum_k exp(P[n][k] + O[i][k]) ) - log(576)
// Shift-invariant -> no max pass. Zero-padded entries -> exp(0)=1.
//
// v11: v10b + incremental tile1 stage-through + halo reuse.
//      v10b (main 47.6us, total 130.5) proved memory-issue duty cycle is
//      the lever (+23% from spreading loads/stores into the K-loops). v11
//      removes the remaining bursts:
//      - tile1 stages only 4 NEW rows (hl1..4); its hl0 row == tile0's hl4,
//        read from buf0 via base-redirect (v9-verified) -> 32 loads, not 40.
//      - loads issue 4/step at ks 0..7 of kloop0; each row is exp-converted
//        and ds_written 3 steps after its loads land (ks 4,6,8,10) -> the
//        serial inter-loop section (vmcnt(0) on 40 loads + 640-expf burst +
//        10 ds_writes) disappears; v1 register lifetime drops from the whole
//        kloop (~80 VGPR) to ~3 steps (~48 VGPR peak).
//      - epi(tile0) spread in kloop1 unchanged (1 f32x4 chunk / step).
// Ledger: issue-spreading +23% (v10b); traffic at floor; more waves null
// (v8); 1 block/CU barriers hurt (v9); NT stores hurt (v7).
// v5:  2-tile pipeline skeleton: 2 blocks/CU, 256thr, 2 barriers.
// v3:  pad via ones-select; Bt coalesced layout; full unroll; dist-2 B.

typedef __bf16 bf16x8 __attribute__((ext_vector_type(8)));
typedef float  f32x4  __attribute__((ext_vector_type(4)));

// ---- BtL[(ks*16 + wv*4 + nt)*64 + q*16 + t16][j] = bf16(exp(off[i][c][p]))
// where inst i = wv*64+nt*16+t16, c = c8*8+j, ks = 2*p + (c8>>2), q = c8&3.
__global__ void mex_prep_b(const float* __restrict__ off, __bf16* __restrict__ Bt) {
    const int i = blockIdx.x * 4 + (threadIdx.x >> 6);  // instance
    const int c = threadIdx.x & 63;                     // channel
    const int c8 = c >> 3, j = c & 7;
    const int wv = i >> 6, nt = (i >> 4) & 3, t16 = i & 15;
    const int q  = c8 & 3;
    const float* oi = off + i * 576;
    #pragma unroll
    for (int p = 0; p < 9; ++p) {
        float v = oi[c * 9 + p];                        // original k = c*9 + p
        const int ks    = p * 2 + (c8 >> 2);
        const int chunk = (ks * 16 + wv * 4 + nt) * 64 + q * 16 + t16;
        Bt[chunk * 8 + j] = (__bf16)__expf(v);
    }
}

// ---- main fused kernel ----------------------------------------------------
__global__ __launch_bounds__(256, 2) void mex_main(
        const float* __restrict__ x,
        const __bf16* __restrict__ Bt,
        float* __restrict__ out) {
    // two buffers: [buf 0..1][hl 0..4][w 0..63][chunk 0..7] bf16x8 = 81920 B
    // buf1 row hl0 is unused (tile1 reads tile0's hl4 instead).
    __shared__ bf16x8 lds8[2 * 2560];

    const int bid = blockIdx.x;      // 0..511
    // XCD-chunked swizzle (512 % 8 == 0 -> bijective)
    const int wid  = ((bid & 7) << 6) | (bid >> 3);
    const int b    = wid >> 3;
    const int j2   = wid & 7;
    const int oh0a = j2 << 2;        // tile0: oh rows oh0a, oh0a+1
    const int oh0b = oh0a + 2;       // tile1: oh rows oh0b, oh0b+1
    const int tid  = threadIdx.x;
    const int wv   = tid >> 6;
    const int lane = tid & 63;

    bf16x8 one8;
    #pragma unroll
    for (int j = 0; j < 8; ++j) one8[j] = (__bf16)1.0f;

    // ---- top pad for tile0 (h_global = -1), only j2 == 0 -----------------
    if (oh0a == 0) {
        #pragma unroll
        for (int i = 0; i < 2; ++i) lds8[tid + i * 256] = one8;
    }

    // staging geometry: thread t -> w-pair wp (w0 = 2*wp), c-chunk c8.
    // swizzled slot c8 ^ (wp&7) == c8 ^ ((w>>1)&7) for both w0, w0+1.
    const int wp  = tid & 31;
    const int w0  = wp << 1;
    const int c8  = tid >> 5;
    const int c8p = c8 ^ (wp & 7);
    const float* xb = x + ((size_t)b << 18) + w0;   // + c*4096 + h*64

    // ---- stage tile0: x -> exp -> bf16 -> swizzled LDS (chained) ---------
    #pragma unroll
    for (int hl = 0; hl < 5; ++hl) {
        const int hg = 2 * oh0a - 1 + hl;           // -1..31
        if (hg >= 0) {                              // block-uniform
            const float* xp = xb + (hg << 6);
            float2 v[8];
            #pragma unroll
            for (int k = 0; k < 8; ++k)
                v[k] = *(const float2*)(xp + (((c8 << 3) + k) << 12));
            bf16x8 ca, cb;
            #pragma unroll
            for (int k = 0; k < 8; ++k) {
                ca[k] = (__bf16)__expf(v[k].x);
                cb[k] = (__bf16)__expf(v[k].y);
            }
            bf16x8* dst = lds8 + hl * 512 + w0 * 8 + c8p;
            dst[0] = ca;        // w = w0
            dst[8] = cb;        // w = w0+1 (same swizzle slot)
        }
    }

    // tile1 NEW rows: buf1 hl = r+1 (r=0..3) <-> hg = 2*oh0a+4+r (4..63).
    float2 v1[4][8];
    const float* xc2 = xb + (((oh0a << 1) + 4) << 6) + ((size_t)c8 << 15);

    // ---- first B fragments (distance-2 pipeline) -------------------------
    const bf16x8* __restrict__ Btv = (const bf16x8*)Bt;
    const int wv4 = wv << 2;
    bf16x8 b0[4], b1[4];
    #pragma unroll
    for (int nt = 0; nt < 4; ++nt) {
        b0[nt] = Btv[(wv4 + nt) * 64 + lane];            // ks = 0
        b1[nt] = Btv[(16 + wv4 + nt) * 64 + lane];       // ks = 1
    }

    const int t16 = tid & 15;
    const int q   = (tid >> 4) & 3;
    int hb[4], wo2[4];
    #pragma unroll
    for (int mt = 0; mt < 4; ++mt) {
        const int m = mt * 16 + t16;
        wo2[mt] = (m & 31) << 1;      // 2*ow
        hb[mt]  = (m >> 5) << 7;      // (2*ohl) * 64
    }
    const float lK = 6.356107660695891f;   // log(576)

    f32x4 acc0[4][4], acc1[4][4];
    #pragma unroll
    for (int mt = 0; mt < 4; ++mt)
        #pragma unroll
        for (int nt = 0; nt < 4; ++nt) acc0[mt][nt] = (f32x4)(0.0f);

    __syncthreads();   // B0: buf0 staged

    // == kloop0: tile0 MFMA + spread tile1 {loads(ks<8), exp+write(4,6,8,10)}
    #pragma unroll
    for (int ks = 0; ks < 18; ++ks) {
        const int p  = ks >> 1;
        const int fh = (p * 11) >> 5;              // p/3 (const after unroll)
        const int fw = p - fh * 3;
        const int ccq = ((ks & 1) << 2) + q;
        bf16x8 a[4];
        #pragma unroll
        for (int mt = 0; mt < 4; ++mt) {
            const int wc  = wo2[mt] + fw - 1;      // w_global, -1..63
            const int pad = wc < 0;                // only fw==0 & ow==0
            const int wcl = pad ? 0 : wc;
            const int row = hb[mt] + fh * 64 + wcl;    // (2*ohl+fh)*64 + w
            bf16x8 vv = lds8[row * 8 + (ccq ^ ((wcl >> 1) & 7))];
            a[mt] = pad ? one8 : vv;
        }
        bf16x8 b2[4];
        if (ks < 16) {
            #pragma unroll
            for (int nt = 0; nt < 4; ++nt)
                b2[nt] = Btv[((ks + 2) * 16 + wv4 + nt) * 64 + lane];
        }
        // spread tile1 x-loads: 4/step at ks 0..7 (row r = ks>>1)
        if (ks < 8) {
            const int r = ks >> 1, u0 = (ks & 1) << 2;
            #pragma unroll
            for (int u = 0; u < 4; ++u)
                v1[r][u0 + u] =
                    *(const float2*)(xc2 + r * 64 + ((u0 + u) << 12));
        }
        // spread tile1 exp+ds_write: row r=(ks-4)>>1 at ks 4,6,8,10
        if (ks >= 4 && ks <= 10 && (ks & 1) == 0) {
            const int r = (ks - 4) >> 1;
            bf16x8 ca, cb;
            #pragma unroll
            for (int k = 0; k < 8; ++k) {
                ca[k] = (__bf16)__expf(v1[r][k].x);
                cb[k] = (__bf16)__expf(v1[r][k].y);
            }
            bf16x8* dst = lds8 + 2560 + (r + 1) * 512 + w0 * 8 + c8p;
            dst[0] = ca;
            dst[8] = cb;
        }
        #pragma unroll
        for (int mt = 0; mt < 4; ++mt)
            #pragma unroll
            for (int nt = 0; nt < 4; ++nt)
                acc0[mt][nt] = __builtin_amdgcn_mfma_f32_16x16x32_bf16(
                    a[mt], b0[nt], acc0[mt][nt], 0, 0, 0);
        #pragma unroll
        for (int nt = 0; nt < 4; ++nt) { b0[nt] = b1[nt]; b1[nt] = b2[nt]; }
    }

    // ---- inter-loop: just B reload + acc1 zero (no staging burst) --------
    #pragma unroll
    for (int nt = 0; nt < 4; ++nt) {
        b0[nt] = Btv[(wv4 + nt) * 64 + lane];            // ks = 0
        b1[nt] = Btv[(16 + wv4 + nt) * 64 + lane];       // ks = 1
    }
    #pragma unroll
    for (int mt = 0; mt < 4; ++mt)
        #pragma unroll
        for (int nt = 0; nt < 4; ++nt) acc1[mt][nt] = (f32x4)(0.0f);

    __syncthreads();   // B1: buf1 rows hl1..4 staged

    // ============ kloop1: tile1 MFMA + spread epi(tile0) chunks ===========
    // A-read: hl = 2*ohl+fh; hl==0 (mt<2 && fh==0) redirects to buf0 hl4.
    #pragma unroll
    for (int ks = 0; ks < 18; ++ks) {
        const int p  = ks >> 1;
        const int fh = (p * 11) >> 5;
        const int fw = p - fh * 3;
        const int ccq = ((ks & 1) << 2) + q;
        bf16x8 a[4];
        #pragma unroll
        for (int mt = 0; mt < 4; ++mt) {
            const int wc  = wo2[mt] + fw - 1;
            const int pad = wc < 0;
            const int wcl = pad ? 0 : wc;
            const bf16x8* bse = (mt < 2 && fh == 0)
                ? (lds8 + 4 * 512)                       // tile0 hl4 (halo)
                : (lds8 + 2560 + (hb[mt] + fh * 64) * 8);
            bf16x8 vv = bse[wcl * 8 + (ccq ^ ((wcl >> 1) & 7))];
            a[mt] = pad ? one8 : vv;
        }
        bf16x8 b2[4];
        if (ks < 16) {
            #pragma unroll
            for (int nt = 0; nt < 4; ++nt)
                b2[nt] = Btv[((ks + 2) * 16 + wv4 + nt) * 64 + lane];
        }
        // spread epi(tile0): one f32x4 chunk (4 logf + 1 store) per step
        if (ks < 16) {
            const int emt = ks >> 2, ent = ks & 3;
            const int m    = emt * 16 + (q << 2);  // C/D: row = q*4 + reg
            const int ohl  = m >> 5;
            const int owi  = m & 31;
            const int orow = (oh0a + ohl) * 32 + owi;
            const int inst = wv * 64 + ent * 16 + t16;
            f32x4 r;
            #pragma unroll
            for (int j = 0; j < 4; ++j)
                r[j] = __logf(acc0[emt][ent][j]) - lK;
            *(f32x4*)(out + (((size_t)b * 256 + inst) * 1024 + orow)) = r;
        }
        #pragma unroll
        for (int mt = 0; mt < 4; ++mt)
            #pragma unroll
            for (int nt = 0; nt < 4; ++nt)
                acc1[mt][nt] = __builtin_amdgcn_mfma_f32_16x16x32_bf16(
                    a[mt], b0[nt], acc1[mt][nt], 0, 0, 0);
        #pragma unroll
        for (int nt = 0; nt < 4; ++nt) { b0[nt] = b1[nt]; b1[nt] = b2[nt]; }
    }

    // ---- epilogue tile1: y = log(S) - log(576) ---------------------------
    #pragma unroll
    for (int mt = 0; mt < 4; ++mt) {
        const int m   = mt * 16 + (q << 2);        // C/D: row = q*4 + reg
        const int ohl = m >> 5;
        const int owi = m & 31;
        const int orow = (oh0b + ohl) * 32 + owi;
        #pragma unroll
        for (int nt = 0; nt < 4; ++nt) {
            const int inst = wv * 64 + nt * 16 + t16;   // C/D: col = t16
            f32x4 r;
            #pragma unroll
            for (int j = 0; j < 4; ++j)
                r[j] = __logf(acc1[mt][nt][j]) - lK;
            *(f32x4*)(out + (((size_t)b * 256 + inst) * 1024 + orow)) = r;
        }
    }
}

extern "C" void kernel_launch(void* const* d_in, const int* in_sizes, int n_in,
                              void* d_out, int out_size, void* d_ws, size_t ws_size,
                              hipStream_t stream) {
    const float* x   = (const float*)d_in[0];   // (64,64,64,64) fp32
    const float* off = (const float*)d_in[1];   // (1,256,64,3,3) fp32
    float* out = (float*)d_out;                 // (64,256,32,32) fp32
    __bf16* Bt = (__bf16*)d_ws;                 // 294912 B

    mex_prep_b<<<64, 256, 0, stream>>>(off, Bt);
    mex_main<<<512, 256, 0, stream>>>(x, Bt, out);
}

// Round 14
// 137.743 us; speedup vs baseline: 1.0073x; 1.0073x over previous
//
#include <hip/hip_runtime.h>
#include <hip/hip_bf16.h>

// Mex forward: B=64,C=64,H=W=64, BLK=(64,3,3), STR=(64,2,2), PAD=(0,1,1),
// NI=256, EPS=1, mean mode. OH=OW=32, K=576, out (64,256,32,32) fp32.
//
// y[n][i] = log( sum_k exp(P[n][k] + O[i][k]) ) - log(576)
// Shift-invariant -> no max pass. Zero-padded entries -> exp(0)=1.
//
// v12: exact v10b skeleton (best measured: main 47.6us, total 130.5) + two
//      minimal same-theory edits:
//      - rows 0..2's exp+ds_write hoisted to kloop0 tail steps ks=12,14,16
//        (their loads finished issuing at ks 3/7/11 -> no mid-loop stalls;
//        the 2/step load spread is UNTOUCHED). Inter-loop burst: 5 rows -> 2.
//      - kloop1 epi chunks pair-ordered (emt=(ks&1)+2*(ks>>3), ent=(ks>>1)&3)
//        so consecutive steps write both 64B halves of one 128B out line ->
//        L2 line merge.
//      v11 lesson (regression, 54us): never re-concentrate issue (4/step
//      loads + mid-loop writes) to enable another optimization; halo reuse
//      saved nothing (FETCH unchanged -> L2 already absorbed it).
// v10b: tile1's 40 x-loads spread 2-4/K-step inside kloop0; epi(tile0)
//      spread 1 f32x4 chunk/K-step inside kloop1. +23% over v5.
// v5:  2-tile pipeline skeleton: 2 blocks/CU, 256thr, 2 barriers.
// v3:  pad via ones-select; Bt coalesced layout; full unroll; dist-2 B.

typedef __bf16 bf16x8 __attribute__((ext_vector_type(8)));
typedef float  f32x4  __attribute__((ext_vector_type(4)));

// ---- BtL[(ks*16 + wv*4 + nt)*64 + q*16 + t16][j] = bf16(exp(off[i][c][p]))
// where inst i = wv*64+nt*16+t16, c = c8*8+j, ks = 2*p + (c8>>2), q = c8&3.
__global__ void mex_prep_b(const float* __restrict__ off, __bf16* __restrict__ Bt) {
    const int i = blockIdx.x * 4 + (threadIdx.x >> 6);  // instance
    const int c = threadIdx.x & 63;                     // channel
    const int c8 = c >> 3, j = c & 7;
    const int wv = i >> 6, nt = (i >> 4) & 3, t16 = i & 15;
    const int q  = c8 & 3;
    const float* oi = off + i * 576;
    #pragma unroll
    for (int p = 0; p < 9; ++p) {
        float v = oi[c * 9 + p];                        // original k = c*9 + p
        const int ks    = p * 2 + (c8 >> 2);
        const int chunk = (ks * 16 + wv * 4 + nt) * 64 + q * 16 + t16;
        Bt[chunk * 8 + j] = (__bf16)__expf(v);
    }
}

// ---- main fused kernel ----------------------------------------------------
__global__ __launch_bounds__(256, 2) void mex_main(
        const float* __restrict__ x,
        const __bf16* __restrict__ Bt,
        float* __restrict__ out) {
    // two buffers: [buf 0..1][hl 0..4][w 0..63][chunk 0..7] bf16x8 = 81920 B
    __shared__ bf16x8 lds8[2 * 2560];

    const int bid = blockIdx.x;      // 0..511
    // XCD-chunked swizzle (512 % 8 == 0 -> bijective)
    const int wid  = ((bid & 7) << 6) | (bid >> 3);
    const int b    = wid >> 3;
    const int j2   = wid & 7;
    const int oh0a = j2 << 2;        // tile0: oh rows oh0a, oh0a+1
    const int oh0b = oh0a + 2;       // tile1: oh rows oh0b, oh0b+1
    const int tid  = threadIdx.x;
    const int wv   = tid >> 6;
    const int lane = tid & 63;

    bf16x8 one8;
    #pragma unroll
    for (int j = 0; j < 8; ++j) one8[j] = (__bf16)1.0f;

    // ---- top pad for tile0 (h_global = -1), only j2 == 0 -----------------
    if (oh0a == 0) {
        #pragma unroll
        for (int i = 0; i < 2; ++i) lds8[tid + i * 256] = one8;
    }

    // staging geometry: thread t -> w-pair wp (w0 = 2*wp), c-chunk c8.
    // swizzled slot c8 ^ (wp&7) == c8 ^ ((w>>1)&7) for both w0, w0+1.
    const int wp  = tid & 31;
    const int w0  = wp << 1;
    const int c8  = tid >> 5;
    const int c8p = c8 ^ (wp & 7);
    const float* xb = x + ((size_t)b << 18) + w0;   // + c*4096 + h*64

    // ---- stage tile0: x -> exp -> bf16 -> swizzled LDS (chained) ---------
    #pragma unroll
    for (int hl = 0; hl < 5; ++hl) {
        const int hg = 2 * oh0a - 1 + hl;           // -1..31
        if (hg >= 0) {                              // block-uniform
            const float* xp = xb + (hg << 6);
            float2 v[8];
            #pragma unroll
            for (int k = 0; k < 8; ++k)
                v[k] = *(const float2*)(xp + (((c8 << 3) + k) << 12));
            bf16x8 ca, cb;
            #pragma unroll
            for (int k = 0; k < 8; ++k) {
                ca[k] = (__bf16)__expf(v[k].x);
                cb[k] = (__bf16)__expf(v[k].y);
            }
            bf16x8* dst = lds8 + hl * 512 + w0 * 8 + c8p;
            dst[0] = ca;        // w = w0
            dst[8] = cb;        // w = w0+1 (same swizzle slot)
        }
    }

    // tile1 load base: hg = 2*oh0b - 1 + hl = 2*oh0a + 3 + hl (>= 3, no pad)
    float2 v1[40];
    const float* xc = xb + (((oh0b << 1) - 1) << 6) + ((size_t)c8 << 15);

    // ---- first B fragments (distance-2 pipeline) -------------------------
    const bf16x8* __restrict__ Btv = (const bf16x8*)Bt;
    const int wv4 = wv << 2;
    bf16x8 b0[4], b1[4];
    #pragma unroll
    for (int nt = 0; nt < 4; ++nt) {
        b0[nt] = Btv[(wv4 + nt) * 64 + lane];            // ks = 0
        b1[nt] = Btv[(16 + wv4 + nt) * 64 + lane];       // ks = 1
    }

    const int t16 = tid & 15;
    const int q   = (tid >> 4) & 3;
    int hb[4], wo2[4];
    #pragma unroll
    for (int mt = 0; mt < 4; ++mt) {
        const int m = mt * 16 + t16;
        wo2[mt] = (m & 31) << 1;      // 2*ow
        hb[mt]  = (m >> 5) << 7;      // (2*ohl) * 64
    }
    const float lK = 6.356107660695891f;   // log(576)

    f32x4 acc0[4][4], acc1[4][4];
    #pragma unroll
    for (int mt = 0; mt < 4; ++mt)
        #pragma unroll
        for (int nt = 0; nt < 4; ++nt) acc0[mt][nt] = (f32x4)(0.0f);

    __syncthreads();   // B0: buf0 staged

    // ================= kloop0: tile0 MFMA + spread tile1 loads ============
    #pragma unroll
    for (int ks = 0; ks < 18; ++ks) {
        const int p  = ks >> 1;
        const int fh = (p * 11) >> 5;              // p/3 (const after unroll)
        const int fw = p - fh * 3;
        const int ccq = ((ks & 1) << 2) + q;
        bf16x8 a[4];
        #pragma unroll
        for (int mt = 0; mt < 4; ++mt) {
            const int wc  = wo2[mt] + fw - 1;      // w_global, -1..63
            const int pad = wc < 0;                // only fw==0 & ow==0
            const int wcl = pad ? 0 : wc;
            const int row = hb[mt] + fh * 64 + wcl;    // (2*ohl+fh)*64 + w
            bf16x8 vv = lds8[row * 8 + (ccq ^ ((wcl >> 1) & 7))];
            a[mt] = pad ? one8 : vv;
        }
        bf16x8 b2[4];
        if (ks < 16) {
            #pragma unroll
            for (int nt = 0; nt < 4; ++nt)
                b2[nt] = Btv[((ks + 2) * 16 + wv4 + nt) * 64 + lane];
        }
        // spread tile1 x-loads: 2/step for ks<16, 4/step for ks=16,17
        if (ks < 16) {
            #pragma unroll
            for (int u = 0; u < 2; ++u) {
                const int k = 2 * ks + u;          // 0..31
                v1[k] = *(const float2*)(xc + (k >> 3) * 64 + ((k & 7) << 12));
            }
        } else {
            #pragma unroll
            for (int u = 0; u < 4; ++u) {
                const int k = 32 + ((ks - 16) << 2) + u;   // 32..39
                v1[k] = *(const float2*)(xc + (k >> 3) * 64 + ((k & 7) << 12));
            }
        }
        // hoisted exp+ds_write of rows 0..2 at ks 12/14/16 (loads of row r
        // finished issuing at ks 4r+3 = 3/7/11 -> landed; spread untouched)
        if (ks == 12 || ks == 14 || ks == 16) {
            const int r = (ks - 12) >> 1;
            bf16x8 ca, cb;
            #pragma unroll
            for (int k = 0; k < 8; ++k) {
                ca[k] = (__bf16)__expf(v1[r * 8 + k].x);
                cb[k] = (__bf16)__expf(v1[r * 8 + k].y);
            }
            bf16x8* dst = lds8 + 2560 + r * 512 + w0 * 8 + c8p;
            dst[0] = ca;
            dst[8] = cb;
        }
        #pragma unroll
        for (int mt = 0; mt < 4; ++mt)
            #pragma unroll
            for (int nt = 0; nt < 4; ++nt)
                acc0[mt][nt] = __builtin_amdgcn_mfma_f32_16x16x32_bf16(
                    a[mt], b0[nt], acc0[mt][nt], 0, 0, 0);
        #pragma unroll
        for (int nt = 0; nt < 4; ++nt) { b0[nt] = b1[nt]; b1[nt] = b2[nt]; }
    }

    // ---- finish-stage tile1: only rows 3,4 remain ------------------------
    #pragma unroll
    for (int hl = 3; hl < 5; ++hl) {
        bf16x8 ca, cb;
        #pragma unroll
        for (int k = 0; k < 8; ++k) {
            ca[k] = (__bf16)__expf(v1[hl * 8 + k].x);
            cb[k] = (__bf16)__expf(v1[hl * 8 + k].y);
        }
        bf16x8* dst = lds8 + 2560 + hl * 512 + w0 * 8 + c8p;
        dst[0] = ca;
        dst[8] = cb;
    }
    #pragma unroll
    for (int nt = 0; nt < 4; ++nt) {
        b0[nt] = Btv[(wv4 + nt) * 64 + lane];            // ks = 0
        b1[nt] = Btv[(16 + wv4 + nt) * 64 + lane];       // ks = 1
    }
    #pragma unroll
    for (int mt = 0; mt < 4; ++mt)
        #pragma unroll
        for (int nt = 0; nt < 4; ++nt) acc1[mt][nt] = (f32x4)(0.0f);

    __syncthreads();   // B1: buf1 staged

    // ============ kloop1: tile1 MFMA + spread epi(tile0) chunks ===========
    #pragma unroll
    for (int ks = 0; ks < 18; ++ks) {
        const int p  = ks >> 1;
        const int fh = (p * 11) >> 5;
        const int fw = p - fh * 3;
        const int ccq = ((ks & 1) << 2) + q;
        bf16x8 a[4];
        #pragma unroll
        for (int mt = 0; mt < 4; ++mt) {
            const int wc  = wo2[mt] + fw - 1;
            const int pad = wc < 0;
            const int wcl = pad ? 0 : wc;
            const int row = hb[mt] + fh * 64 + wcl;
            bf16x8 vv = lds8[2560 + row * 8 + (ccq ^ ((wcl >> 1) & 7))];
            a[mt] = pad ? one8 : vv;
        }
        bf16x8 b2[4];
        if (ks < 16) {
            #pragma unroll
            for (int nt = 0; nt < 4; ++nt)
                b2[nt] = Btv[((ks + 2) * 16 + wv4 + nt) * 64 + lane];
        }
        // spread epi(tile0), pair-ordered: consecutive steps write the two
        // 64B halves (emt, emt+1) of one 128B out line -> L2 merge.
        if (ks < 16) {
            const int emt = (ks & 1) + ((ks >> 3) << 1);
            const int ent = (ks >> 1) & 3;
            const int m    = emt * 16 + (q << 2);  // C/D: row = q*4 + reg
            const int ohl  = m >> 5;
            const int owi  = m & 31;
            const int orow = (oh0a + ohl) * 32 + owi;
            const int inst = wv * 64 + ent * 16 + t16;
            f32x4 r;
            #pragma unroll
            for (int j = 0; j < 4; ++j)
                r[j] = __logf(acc0[emt][ent][j]) - lK;
            *(f32x4*)(out + (((size_t)b * 256 + inst) * 1024 + orow)) = r;
        }
        #pragma unroll
        for (int mt = 0; mt < 4; ++mt)
            #pragma unroll
            for (int nt = 0; nt < 4; ++nt)
                acc1[mt][nt] = __builtin_amdgcn_mfma_f32_16x16x32_bf16(
                    a[mt], b0[nt], acc1[mt][nt], 0, 0, 0);
        #pragma unroll
        for (int nt = 0; nt < 4; ++nt) { b0[nt] = b1[nt]; b1[nt] = b2[nt]; }
    }

    // ---- epilogue tile1: y = log(S) - log(576) ---------------------------
    #pragma unroll
    for (int mt = 0; mt < 4; ++mt) {
        const int m   = mt * 16 + (q << 2);        // C/D: row = q*4 + reg
        const int ohl = m >> 5;
        const int owi = m & 31;
        const int orow = (oh0b + ohl) * 32 + owi;
        #pragma unroll
        for (int nt = 0; nt < 4; ++nt) {
            const int inst = wv * 64 + nt * 16 + t16;   // C/D: col = t16
            f32x4 r;
            #pragma unroll
            for (int j = 0; j < 4; ++j)
                r[j] = __logf(acc1[mt][nt][j]) - lK;
            *(f32x4*)(out + (((size_t)b * 256 + inst) * 1024 + orow)) = r;
        }
    }
}

extern "C" void kernel_launch(void* const* d_in, const int* in_sizes, int n_in,
                              void* d_out, int out_size, void* d_ws, size_t ws_size,
                              hipStream_t stream) {
    const float* x   = (const float*)d_in[0];   // (64,64,64,64) fp32
    const float* off = (const float*)d_in[1];   // (1,256,64,3,3) fp32
    float* out = (float*)d_out;                 // (64,256,32,32) fp32
    __bf16* Bt = (__bf16*)d_ws;                 // 294912 B

    mex_prep_b<<<64, 256, 0, stream>>>(off, Bt);
    mex_main<<<512, 256, 0, stream>>>(x, Bt, out);
}

// Round 15
// 130.450 us; speedup vs baseline: 1.0637x; 1.0559x over previous
//
#include <hip/hip_runtime.h>
#include <hip/hip_bf16.h>

// Mex forward: B=64,C=64,H=W=64, BLK=(64,3,3), STR=(64,2,2), PAD=(0,1,1),
// NI=256, EPS=1, mean mode. OH=OW=32, K=576, out (64,256,32,32) fp32.
//
// y[n][i] = log( sum_k exp(P[n][k] + O[i][k]) ) - log(576)
// Shift-invariant -> no max pass. Zero-padded entries -> exp(0)=1.
//
// v13 == v10b byte-exact revert (measured best: main 47.6us, total 130.5us).
//      v11 (-6.5us) and v12 (-3us) both proved the kloop is
//      schedule-saturated: inserting ANY extra LDS write into it costs more
//      than the inter-loop burst it removes. Schedule:
//      - tile1's 40 x-loads issue 2-4 per K-step inside kloop0 (spreads HBM
//        issue over the whole loop; was one burst -> chip-wide phase
//        oscillation capping HBM at 3.0/6.3 TB/s);
//      - epi(tile0) fused into kloop1: one f32x4 chunk (4 logf + 1 store)
//        per K-step.
//      Ledger: issue-spreading +23% (v10b); traffic at floor; more waves
//      null (v8); 1 block/CU barriers hurt (v9); NT stores hurt (v7);
//      mid-loop LDS writes hurt (v11, v12).
// v5:  2-tile pipeline skeleton: 2 blocks/CU, 256thr, 2 barriers.
// v3:  pad via ones-select; Bt coalesced layout; full unroll; dist-2 B.

typedef __bf16 bf16x8 __attribute__((ext_vector_type(8)));
typedef float  f32x4  __attribute__((ext_vector_type(4)));

// ---- BtL[(ks*16 + wv*4 + nt)*64 + q*16 + t16][j] = bf16(exp(off[i][c][p]))
// where inst i = wv*64+nt*16+t16, c = c8*8+j, ks = 2*p + (c8>>2), q = c8&3.
__global__ void mex_prep_b(const float* __restrict__ off, __bf16* __restrict__ Bt) {
    const int i = blockIdx.x * 4 + (threadIdx.x >> 6);  // instance
    const int c = threadIdx.x & 63;                     // channel
    const int c8 = c >> 3, j = c & 7;
    const int wv = i >> 6, nt = (i >> 4) & 3, t16 = i & 15;
    const int q  = c8 & 3;
    const float* oi = off + i * 576;
    #pragma unroll
    for (int p = 0; p < 9; ++p) {
        float v = oi[c * 9 + p];                        // original k = c*9 + p
        const int ks    = p * 2 + (c8 >> 2);
        const int chunk = (ks * 16 + wv * 4 + nt) * 64 + q * 16 + t16;
        Bt[chunk * 8 + j] = (__bf16)__expf(v);
    }
}

// ---- main fused kernel ----------------------------------------------------
__global__ __launch_bounds__(256, 2) void mex_main(
        const float* __restrict__ x,
        const __bf16* __restrict__ Bt,
        float* __restrict__ out) {
    // two buffers: [buf 0..1][hl 0..4][w 0..63][chunk 0..7] bf16x8 = 81920 B
    __shared__ bf16x8 lds8[2 * 2560];

    const int bid = blockIdx.x;      // 0..511
    // XCD-chunked swizzle (512 % 8 == 0 -> bijective)
    const int wid  = ((bid & 7) << 6) | (bid >> 3);
    const int b    = wid >> 3;
    const int j2   = wid & 7;
    const int oh0a = j2 << 2;        // tile0: oh rows oh0a, oh0a+1
    const int oh0b = oh0a + 2;       // tile1: oh rows oh0b, oh0b+1
    const int tid  = threadIdx.x;
    const int wv   = tid >> 6;
    const int lane = tid & 63;

    bf16x8 one8;
    #pragma unroll
    for (int j = 0; j < 8; ++j) one8[j] = (__bf16)1.0f;

    // ---- top pad for tile0 (h_global = -1), only j2 == 0 -----------------
    if (oh0a == 0) {
        #pragma unroll
        for (int i = 0; i < 2; ++i) lds8[tid + i * 256] = one8;
    }

    // staging geometry: thread t -> w-pair wp (w0 = 2*wp), c-chunk c8.
    // swizzled slot c8 ^ (wp&7) == c8 ^ ((w>>1)&7) for both w0, w0+1.
    const int wp  = tid & 31;
    const int w0  = wp << 1;
    const int c8  = tid >> 5;
    const int c8p = c8 ^ (wp & 7);
    const float* xb = x + ((size_t)b << 18) + w0;   // + c*4096 + h*64

    // ---- stage tile0: x -> exp -> bf16 -> swizzled LDS (chained) ---------
    #pragma unroll
    for (int hl = 0; hl < 5; ++hl) {
        const int hg = 2 * oh0a - 1 + hl;           // -1..31
        if (hg >= 0) {                              // block-uniform
            const float* xp = xb + (hg << 6);
            float2 v[8];
            #pragma unroll
            for (int k = 0; k < 8; ++k)
                v[k] = *(const float2*)(xp + (((c8 << 3) + k) << 12));
            bf16x8 ca, cb;
            #pragma unroll
            for (int k = 0; k < 8; ++k) {
                ca[k] = (__bf16)__expf(v[k].x);
                cb[k] = (__bf16)__expf(v[k].y);
            }
            bf16x8* dst = lds8 + hl * 512 + w0 * 8 + c8p;
            dst[0] = ca;        // w = w0
            dst[8] = cb;        // w = w0+1 (same swizzle slot)
        }
    }

    // tile1 load base: hg = 2*oh0b - 1 + hl = 2*oh0a + 3 + hl (>= 3, no pad)
    float2 v1[40];
    const float* xc = xb + (((oh0b << 1) - 1) << 6) + ((size_t)c8 << 15);

    // ---- first B fragments (distance-2 pipeline) -------------------------
    const bf16x8* __restrict__ Btv = (const bf16x8*)Bt;
    const int wv4 = wv << 2;
    bf16x8 b0[4], b1[4];
    #pragma unroll
    for (int nt = 0; nt < 4; ++nt) {
        b0[nt] = Btv[(wv4 + nt) * 64 + lane];            // ks = 0
        b1[nt] = Btv[(16 + wv4 + nt) * 64 + lane];       // ks = 1
    }

    const int t16 = tid & 15;
    const int q   = (tid >> 4) & 3;
    int hb[4], wo2[4];
    #pragma unroll
    for (int mt = 0; mt < 4; ++mt) {
        const int m = mt * 16 + t16;
        wo2[mt] = (m & 31) << 1;      // 2*ow
        hb[mt]  = (m >> 5) << 7;      // (2*ohl) * 64
    }
    const float lK = 6.356107660695891f;   // log(576)

    f32x4 acc0[4][4], acc1[4][4];
    #pragma unroll
    for (int mt = 0; mt < 4; ++mt)
        #pragma unroll
        for (int nt = 0; nt < 4; ++nt) acc0[mt][nt] = (f32x4)(0.0f);

    __syncthreads();   // B0: buf0 staged

    // ================= kloop0: tile0 MFMA + spread tile1 loads ============
    #pragma unroll
    for (int ks = 0; ks < 18; ++ks) {
        const int p  = ks >> 1;
        const int fh = (p * 11) >> 5;              // p/3 (const after unroll)
        const int fw = p - fh * 3;
        const int ccq = ((ks & 1) << 2) + q;
        bf16x8 a[4];
        #pragma unroll
        for (int mt = 0; mt < 4; ++mt) {
            const int wc  = wo2[mt] + fw - 1;      // w_global, -1..63
            const int pad = wc < 0;                // only fw==0 & ow==0
            const int wcl = pad ? 0 : wc;
            const int row = hb[mt] + fh * 64 + wcl;    // (2*ohl+fh)*64 + w
            bf16x8 vv = lds8[row * 8 + (ccq ^ ((wcl >> 1) & 7))];
            a[mt] = pad ? one8 : vv;
        }
        bf16x8 b2[4];
        if (ks < 16) {
            #pragma unroll
            for (int nt = 0; nt < 4; ++nt)
                b2[nt] = Btv[((ks + 2) * 16 + wv4 + nt) * 64 + lane];
        }
        // spread tile1 x-loads: 2/step for ks<16, 4/step for ks=16,17
        if (ks < 16) {
            #pragma unroll
            for (int u = 0; u < 2; ++u) {
                const int k = 2 * ks + u;          // 0..31
                v1[k] = *(const float2*)(xc + (k >> 3) * 64 + ((k & 7) << 12));
            }
        } else {
            #pragma unroll
            for (int u = 0; u < 4; ++u) {
                const int k = 32 + ((ks - 16) << 2) + u;   // 32..39
                v1[k] = *(const float2*)(xc + (k >> 3) * 64 + ((k & 7) << 12));
            }
        }
        #pragma unroll
        for (int mt = 0; mt < 4; ++mt)
            #pragma unroll
            for (int nt = 0; nt < 4; ++nt)
                acc0[mt][nt] = __builtin_amdgcn_mfma_f32_16x16x32_bf16(
                    a[mt], b0[nt], acc0[mt][nt], 0, 0, 0);
        #pragma unroll
        for (int nt = 0; nt < 4; ++nt) { b0[nt] = b1[nt]; b1[nt] = b2[nt]; }
    }

    // ---- finish-stage tile1 (loads landed under kloop0) ------------------
    #pragma unroll
    for (int hl = 0; hl < 5; ++hl) {
        bf16x8 ca, cb;
        #pragma unroll
        for (int k = 0; k < 8; ++k) {
            ca[k] = (__bf16)__expf(v1[hl * 8 + k].x);
            cb[k] = (__bf16)__expf(v1[hl * 8 + k].y);
        }
        bf16x8* dst = lds8 + 2560 + hl * 512 + w0 * 8 + c8p;
        dst[0] = ca;
        dst[8] = cb;
    }
    #pragma unroll
    for (int nt = 0; nt < 4; ++nt) {
        b0[nt] = Btv[(wv4 + nt) * 64 + lane];            // ks = 0
        b1[nt] = Btv[(16 + wv4 + nt) * 64 + lane];       // ks = 1
    }
    #pragma unroll
    for (int mt = 0; mt < 4; ++mt)
        #pragma unroll
        for (int nt = 0; nt < 4; ++nt) acc1[mt][nt] = (f32x4)(0.0f);

    __syncthreads();   // B1: buf1 staged

    // ============ kloop1: tile1 MFMA + spread epi(tile0) chunks ===========
    #pragma unroll
    for (int ks = 0; ks < 18; ++ks) {
        const int p  = ks >> 1;
        const int fh = (p * 11) >> 5;
        const int fw = p - fh * 3;
        const int ccq = ((ks & 1) << 2) + q;
        bf16x8 a[4];
        #pragma unroll
        for (int mt = 0; mt < 4; ++mt) {
            const int wc  = wo2[mt] + fw - 1;
            const int pad = wc < 0;
            const int wcl = pad ? 0 : wc;
            const int row = hb[mt] + fh * 64 + wcl;
            bf16x8 vv = lds8[2560 + row * 8 + (ccq ^ ((wcl >> 1) & 7))];
            a[mt] = pad ? one8 : vv;
        }
        bf16x8 b2[4];
        if (ks < 16) {
            #pragma unroll
            for (int nt = 0; nt < 4; ++nt)
                b2[nt] = Btv[((ks + 2) * 16 + wv4 + nt) * 64 + lane];
        }
        // spread epi(tile0): one f32x4 chunk (4 logf + 1 store) per step
        if (ks < 16) {
            const int emt = ks >> 2, ent = ks & 3;
            const int m    = emt * 16 + (q << 2);  // C/D: row = q*4 + reg
            const int ohl  = m >> 5;
            const int owi  = m & 31;
            const int orow = (oh0a + ohl) * 32 + owi;
            const int inst = wv * 64 + ent * 16 + t16;
            f32x4 r;
            #pragma unroll
            for (int j = 0; j < 4; ++j)
                r[j] = __logf(acc0[emt][ent][j]) - lK;
            *(f32x4*)(out + (((size_t)b * 256 + inst) * 1024 + orow)) = r;
        }
        #pragma unroll
        for (int mt = 0; mt < 4; ++mt)
            #pragma unroll
            for (int nt = 0; nt < 4; ++nt)
                acc1[mt][nt] = __builtin_amdgcn_mfma_f32_16x16x32_bf16(
                    a[mt], b0[nt], acc1[mt][nt], 0, 0, 0);
        #pragma unroll
        for (int nt = 0; nt < 4; ++nt) { b0[nt] = b1[nt]; b1[nt] = b2[nt]; }
    }

    // ---- epilogue tile1: y = log(S) - log(576) ---------------------------
    #pragma unroll
    for (int mt = 0; mt < 4; ++mt) {
        const int m   = mt * 16 + (q << 2);        // C/D: row = q*4 + reg
        const int ohl = m >> 5;
        const int owi = m & 31;
        const int orow = (oh0b + ohl) * 32 + owi;
        #pragma unroll
        for (int nt = 0; nt < 4; ++nt) {
            const int inst = wv * 64 + nt * 16 + t16;   // C/D: col = t16
            f32x4 r;
            #pragma unroll
            for (int j = 0; j < 4; ++j)
                r[j] = __logf(acc1[mt][nt][j]) - lK;
            *(f32x4*)(out + (((size_t)b * 256 + inst) * 1024 + orow)) = r;
        }
    }
}

extern "C" void kernel_launch(void* const* d_in, const int* in_sizes, int n_in,
                              void* d_out, int out_size, void* d_ws, size_t ws_size,
                              hipStream_t stream) {
    const float* x   = (const float*)d_in[0];   // (64,64,64,64) fp32
    const float* off = (const float*)d_in[1];   // (1,256,64,3,3) fp32
    float* out = (float*)d_out;                 // (64,256,32,32) fp32
    __bf16* Bt = (__bf16*)d_ws;                 // 294912 B

    mex_prep_b<<<64, 256, 0, stream>>>(off, Bt);
    mex_main<<<512, 256, 0, stream>>>(x, Bt, out);
}